// Round 3
// baseline (78.792 us; speedup 1.0000x reference)
//
#include <hip/hip_runtime.h>
#include <math.h>

#define BS    8192
#define NCTX  28
#define DM    28
#define IPB   4
#define TPI   32
#define BLOCK (IPB*TPI)     // 128 threads, 2 waves
#define XSTRIDE 29          // padded x row stride (floats); odd -> conflict-free b32
#define QSTRIDE 28          // q row stride after reuse: 112 B, 16B-aligned
#define WTS   96            // transposed-weight row stride (floats), 384B rows

// transposed weights: g_wt[w*WTS + c] with c: 0..27=Wq col, 28..55=Wk, 56..83=Wv
__device__ float g_wt[NCTX * WTS];

__global__ void transpose_weights(const float* __restrict__ Wq,
                                  const float* __restrict__ Wk,
                                  const float* __restrict__ Wv)
{
    int t = threadIdx.x;
    for (int i = t; i < DM * DM; i += blockDim.x) {
        int c = i / DM, w = i % DM;
        g_wt[w*WTS + c]      = Wq[c*DM + w];
        g_wt[w*WTS + 28 + c] = Wk[c*DM + w];
        g_wt[w*WTS + 56 + c] = Wv[c*DM + w];
    }
}

__global__ __launch_bounds__(BLOCK, 4) void l1att_fused(
    const float* __restrict__ x,
    const float* __restrict__ bq, const float* __restrict__ bk,
    const float* __restrict__ bv,
    const float* __restrict__ W1, const float* __restrict__ b1,
    const float* __restrict__ W2, const float* __restrict__ b2,
    float* __restrict__ out)
{
    __shared__ float xs[IPB][NCTX*XSTRIDE];  // x rows (stride 29); later q rows (stride 28)
    __shared__ float l1_lds[IPB][NCTX];
    __shared__ float h_lds[IPB][20];

    const int t    = threadIdx.x;
    const int item = t >> 5;
    const int m    = t & 31;
    const int b    = blockIdx.x * IPB + item;
    const bool active = (m < NCTX);

    // packed accumulators: pairs along c
    float2 aq[14], ak[14], av[14];

    if (active) {
        // ---- stage own x row into padded LDS ----
        const float4* xp = (const float4*)(x + ((size_t)b * NCTX + m) * DM);
        float xt[DM];
        #pragma unroll
        for (int i = 0; i < DM/4; ++i) {
            float4 v4 = xp[i];
            xt[4*i+0]=v4.x; xt[4*i+1]=v4.y; xt[4*i+2]=v4.z; xt[4*i+3]=v4.w;
        }
        #pragma unroll
        for (int w = 0; w < DM; ++w) xs[item][m*XSTRIDE + w] = xt[w];

        // ---- init accumulators with biases (uniform s_loads) ----
        const float2* bq2 = (const float2*)bq;
        const float2* bk2 = (const float2*)bk;
        const float2* bv2 = (const float2*)bv;
        #pragma unroll
        for (int i = 0; i < 14; ++i) { aq[i] = bq2[i]; ak[i] = bk2[i]; av[i] = bv2[i]; }

        // ---- qkv: runtime-w loop; per iter: 1 ds_read + ~5 wide s_loads + 42 pk_fma ----
        const float* xrow = &xs[item][m*XSTRIDE];
        for (int w = 0; w < DM; ++w) {
            float xw = xrow[w];
            float2 x2 = make_float2(xw, xw);
            const float2* wr = (const float2*)(&g_wt[w*WTS]);   // uniform, contiguous
            #pragma unroll
            for (int i = 0; i < 14; ++i) {
                float2 wq2 = wr[i];
                float2 wk2 = wr[14+i];
                float2 wv2 = wr[28+i];
                asm("v_pk_fma_f32 %0, %1, %2, %0" : "+v"(aq[i]) : "v"(x2), "s"(wq2));
                asm("v_pk_fma_f32 %0, %1, %2, %0" : "+v"(ak[i]) : "v"(x2), "s"(wk2));
                asm("v_pk_fma_f32 %0, %1, %2, %0" : "+v"(av[i]) : "v"(x2), "s"(wv2));
            }
        }
    }
    __syncthreads();   // everyone done with x before q overwrites the region

    if (active) {
        // ---- publish q row at stride 28 (16B-aligned) ----
        float4* qdst = (float4*)(&xs[item][m*QSTRIDE]);
        #pragma unroll
        for (int i = 0; i < 7; ++i)
            qdst[i] = make_float4(aq[2*i].x, aq[2*i].y, aq[2*i+1].x, aq[2*i+1].y);
    }
    __syncthreads();

    if (active) {
        // ---- unpack k, v to scalar names (pure register renames, static) ----
        float kr[DM], vr[DM];
        #pragma unroll
        for (int i = 0; i < 14; ++i) {
            kr[2*i] = ak[i].x; kr[2*i+1] = ak[i].y;
            vr[2*i] = av[i].x; vr[2*i+1] = av[i].y;
        }

        // ---- L1 attention + row-dot with v ----
        const float scale = -0.18898223650461363f;   // -1/sqrt(28)
        const float* qbase = &xs[item][0];
        float acc = 0.f;
        #pragma unroll
        for (int j = 0; j < NCTX; ++j) {
            const float4* qj = (const float4*)(qbase + j*QSTRIDE);  // uniform broadcast
            float s0 = 0.f, s1 = 0.f, s2 = 0.f, s3 = 0.f;
            #pragma unroll
            for (int w4 = 0; w4 < DM/4; ++w4) {
                float4 qv = qj[w4];
                s0 += fabsf(qv.x - kr[4*w4+0]);
                s1 += fabsf(qv.y - kr[4*w4+1]);
                s2 += fabsf(qv.z - kr[4*w4+2]);
                s3 += fabsf(qv.w - kr[4*w4+3]);
            }
            float a = (j == m) ? 1.0f : scale * ((s0 + s1) + (s2 + s3));
            acc = fmaf(vr[j], a, acc);
        }
        l1_lds[item][m] = acc;
    }
    __syncthreads();

    if (m < 20) {
        float a = b1[m];
        #pragma unroll
        for (int w = 0; w < NCTX; ++w) a += l1_lds[item][w] * W1[m*NCTX + w];
        h_lds[item][m] = fmaxf(a, 0.f);
    }
    __syncthreads();

    if (m < 10) {
        float a = b2[m];
        #pragma unroll
        for (int w = 0; w < 20; ++w) a += h_lds[item][w] * W2[m*20 + w];
        out[(size_t)b*10 + m] = a;
    }
}

extern "C" void kernel_launch(void* const* d_in, const int* in_sizes, int n_in,
                              void* d_out, int out_size, void* d_ws, size_t ws_size,
                              hipStream_t stream) {
    const float* x  = (const float*)d_in[0];
    const float* Wq = (const float*)d_in[1];
    const float* bq = (const float*)d_in[2];
    const float* Wk = (const float*)d_in[3];
    const float* bk = (const float*)d_in[4];
    const float* Wv = (const float*)d_in[5];
    const float* bv = (const float*)d_in[6];
    const float* W1 = (const float*)d_in[7];
    const float* b1 = (const float*)d_in[8];
    const float* W2 = (const float*)d_in[9];
    const float* b2 = (const float*)d_in[10];
    float* out = (float*)d_out;

    hipLaunchKernelGGL(transpose_weights, dim3(1), dim3(256), 0, stream, Wq, Wk, Wv);

    dim3 grid(BS / IPB), block(BLOCK);
    hipLaunchKernelGGL(l1att_fused, grid, block, 0, stream,
                       x, bq, bk, bv, W1, b1, W2, b2, out);
}